// Round 9
// baseline (556.563 us; speedup 1.0000x reference)
//
#include <hip/hip_runtime.h>

// LinearAttention fused, MFMA (bf16 in / fp32 acc). 3-kernel pipeline.
//   kW: zero O16/Zg accumulators + pre-convert w_qkv (384x64) -> bf16
//   kA: LN1 -> per head: {k,v GEMM -> exp(k) -> ctx cc[2][2] over own cols ->
//       per-wave atomicAdd into O16 slice}. Z via shfl_xor -> Zp -> atomicAdd Zg.
//       KEY (r8 lesson): cc[h] is final per h-iteration; keeping cc[4][2][2] live
//       across the h-loop forced a 64-float/thread scratch spill (WRITE 66MB == the
//       spill, VGPR stuck at 64-80 for every launch_bounds setting). Finalizing
//       per head cuts live acc 64->16 floats; demand ~85 fits the compiler budget.
//   kB: LN1 -> bx regs -> [Mg build from 16 O-slices] -> q GEMM -> softmax -> PV -> LN2.
//   Plain __launch_bounds__(256) on both (only non-spill codegen observed; the
//   min-waves arg made codegen WORSE: (256,3)->76 VGPR, (256,4)->64).
#define NCOL 131072
#define CH 64

typedef float floatx4 __attribute__((ext_vector_type(4)));
typedef __bf16 bf16x8 __attribute__((ext_vector_type(8)));
typedef unsigned int u32x4 __attribute__((ext_vector_type(4)));
typedef unsigned int u32x2 __attribute__((ext_vector_type(2)));

union FragU { u32x4 q; bf16x8 v; unsigned short us[8]; };

__device__ __forceinline__ unsigned short bfb(float f){
  union { __bf16 h; unsigned short s; } u; u.h = (__bf16)f; return u.s;
}
__device__ __forceinline__ float bf2f(unsigned short h){
  union { unsigned u; float f; } x{(unsigned)h << 16};
  return x.f;
}

// LN over 64 channels for column (thread t), write bf16 column to xn_s[t][0..63], stride 72.
__device__ __forceinline__ void ln_stage(const float* __restrict__ xp,
    const float* __restrict__ g, const float* __restrict__ bb,
    unsigned short* __restrict__ xn_s, int t)
{
  float xv[64]; float s = 0.f, ss = 0.f;
  #pragma unroll
  for (int c = 0; c < 64; c++){ float u = xp[(long)c*NCOL]; xv[c] = u; s += u; ss = fmaf(u,u,ss); }
  const float mean = s * (1.f/64.f);
  const float rstd = rsqrtf(ss * (1.f/64.f) - mean*mean + 1e-5f);
  #pragma unroll
  for (int c = 0; c < 64; c++) xv[c] = (xv[c]-mean)*rstd*g[c] + bb[c];
  #pragma unroll
  for (int j = 0; j < 8; j++){
    FragU u;
    #pragma unroll
    for (int e = 0; e < 8; e++) u.v[e] = (__bf16)xv[j*8+e];
    *(u32x4*)(xn_s + t*72 + j*8) = u.q;
  }
}

// ---------------- kW: zero O16+Zg, convert wqkv -> bf16 ----------------
__global__ __launch_bounds__(256) void kW(
    const float* __restrict__ wqkv, unsigned short* __restrict__ wbf, float* __restrict__ Oz)
{
  const int i = blockIdx.x*256 + threadIdx.x;   // grid 516 -> 132096 threads
  if (i < 24576) wbf[i] = bfb(wqkv[i]);         // 384*64
  if (i < 131328) Oz[i] = 0.f;                  // O16 (131072) + Zg (256)
}

// ---------------- kA ----------------
__global__ __launch_bounds__(256) void kA(
    const float* __restrict__ x, const float* __restrict__ g1, const float* __restrict__ b1,
    const unsigned short* __restrict__ wbf, float* __restrict__ O16, float* __restrict__ Zg)
{
  __shared__ __align__(16) char smem[36864];
  unsigned short* xn_s = (unsigned short*)smem;             // [0,36864) staging (dead after bx)
  unsigned short* ek_s = (unsigned short*)smem;             // [0,16896)   alias
  unsigned short* v_s  = (unsigned short*)(smem + 16896);   // [16896,33792) alias
  float* Zp            = (float*)(smem + 33792);            // [33792,35840) : [w][128]

  const int t = threadIdx.x;
  const int bid = blockIdx.x;
  const int b = bid >> 9;
  const long col0 = (long)(bid & 511) * 256;
  const int w = t >> 6, lane = t & 63, qq = lane >> 4, l16 = lane & 15;

  ln_stage(x + (long)b*CH*NCOL + col0 + t, g1, b1, xn_s, t);
  // in-wave read-back of own wave's columns (DS in-order per wave; no barrier)
  FragU bx[4][2];
  #pragma unroll
  for (int nt = 0; nt < 4; nt++)
    #pragma unroll
    for (int ks = 0; ks < 2; ks++)
      bx[nt][ks].q = *(const u32x4*)(xn_s + ((4*w+nt)*16 + l16)*72 + ks*32 + qq*8);
  __syncthreads();   // alias guard: all waves' bx loaded before ek/v/Zp overwrite xn

  const long obase0 = ((long)(b*16 + ((bid*4 + w) & 15)))*4096;  // this wave's O slice

  #pragma unroll
  for (int h = 0; h < 4; h++){
    float zr[8];
    #pragma unroll
    for (int j = 0; j < 8; j++) zr[j] = 0.f;
    // k (rt 0,1) and v (rt 2,3) GEMM, 16 rows per rt; wave-private column slices
    #pragma unroll
    for (int rt = 0; rt < 4; rt++){
      const int row0 = ((rt < 2) ? 128 : 256) + h*32 + (rt & 1)*16;
      const unsigned short* wr = wbf + (row0 + l16)*64 + qq*8;
      FragU a0, a1;
      a0.q = *(const u32x4*)wr;
      a1.q = *(const u32x4*)(wr + 32);
      unsigned short* dst = ((rt < 2) ? ek_s : v_s) + ((rt & 1)*16 + qq*4)*264;
      #pragma unroll
      for (int nt = 0; nt < 4; nt++){
        floatx4 c = floatx4{0.f,0.f,0.f,0.f};
        c = __builtin_amdgcn_mfma_f32_16x16x32_bf16(a0.v, bx[nt][0].v, c, 0, 0, 0);
        c = __builtin_amdgcn_mfma_f32_16x16x32_bf16(a1.v, bx[nt][1].v, c, 0, 0, 0);
        const int colb = (4*w+nt)*16 + l16;
        if (rt < 2){
          #pragma unroll
          for (int r = 0; r < 4; r++){
            const float e = __expf(c[r]);
            dst[r*264 + colb] = bfb(e);
            zr[(rt & 1)*4 + r] += e;
          }
        } else {
          #pragma unroll
          for (int r = 0; r < 4; r++) dst[r*264 + colb] = bfb(c[r]);
        }
      }
    }
    // Z partial for this wave's 64 cols: butterfly over l16 lanes
    #pragma unroll
    for (int j = 0; j < 8; j++){
      float v = zr[j];
      v += __shfl_xor(v, 1, 64); v += __shfl_xor(v, 2, 64);
      v += __shfl_xor(v, 4, 64); v += __shfl_xor(v, 8, 64);
      if (l16 == 0) Zp[w*128 + h*32 + (j >> 2)*16 + qq*4 + (j & 3)] = v;
    }
    // ctx MFMAs for THIS head over own cols; cc is head-local (16 regs, no spill)
    floatx4 cc[2][2];
    #pragma unroll
    for (int dt = 0; dt < 2; dt++)
      #pragma unroll
      for (int et = 0; et < 2; et++)
        cc[dt][et] = floatx4{0.f,0.f,0.f,0.f};
    #pragma unroll
    for (int kk = 0; kk < 2; kk++){
      const int ks2 = 2*w + kk;
      FragU ae[2], bv[2];
      #pragma unroll
      for (int dt = 0; dt < 2; dt++) ae[dt].q = *(const u32x4*)(ek_s + (dt*16 + l16)*264 + ks2*32 + qq*8);
      #pragma unroll
      for (int et = 0; et < 2; et++) bv[et].q = *(const u32x4*)(v_s + (et*16 + l16)*264 + ks2*32 + qq*8);
      #pragma unroll
      for (int dt = 0; dt < 2; dt++)
        #pragma unroll
        for (int et = 0; et < 2; et++)
          cc[dt][et] = __builtin_amdgcn_mfma_f32_16x16x32_bf16(ae[dt].v, bv[et].v, cc[dt][et], 0, 0, 0);
    }
    // finalize head h NOW: per-wave partial straight into the L2-resident O slice
    // (fire-and-forget f32 atomics; 16/lane/head; no waits, no barriers)
    #pragma unroll
    for (int dt = 0; dt < 2; dt++)
      #pragma unroll
      for (int et = 0; et < 2; et++){
        const long p = obase0 + h*1024 + (dt*2 + et)*256 + lane*4;
        #pragma unroll
        for (int j = 0; j < 4; j++) atomicAdd(&O16[p + j], cc[dt][et][j]);
      }
  }
  __syncthreads();   // Zp writes visible

  if (t < 128){
    const float z = Zp[t] + Zp[128 + t] + Zp[256 + t] + Zp[384 + t];
    atomicAdd(&Zg[b*128 + t], z);   // t == h*32+d
  }
}

// ---------------- kB (kM folded in) ----------------
__global__ __launch_bounds__(256) void kB(
    const float* __restrict__ x, const float* __restrict__ g1, const float* __restrict__ b1,
    const unsigned short* __restrict__ wbf, const float* __restrict__ O16,
    const float* __restrict__ Zg, const float* __restrict__ wout,
    const float* __restrict__ bout, const float* __restrict__ g2, const float* __restrict__ b2,
    float* __restrict__ y)
{
  __shared__ __align__(16) char smem[37632];
  unsigned short* xn_s = (unsigned short*)smem;             // [0,36864) staging (dead after bx)
  float* O_s           = (float*)smem;                      // [0,16384)  alias (Mg phase)
  unsigned short* qs_s = (unsigned short*)smem;             // [0,20480)  alias (h-loop)
  unsigned short* Mg_s = (unsigned short*)(smem + 20480);   // [20480,36864)
  float* sp            = (float*)(smem + 36864);            // 192 floats

  const int t = threadIdx.x;
  const int bid = blockIdx.x;
  const int b = bid >> 9;
  const long col0 = (long)(bid & 511) * 256;
  const int w = t >> 6, lane = t & 63, qq = lane >> 4, l16 = lane & 15;

  if (t < 64){ sp[t] = bout[t]; sp[64+t] = g2[t]; sp[128+t] = b2[t]; }
  ln_stage(x + (long)b*CH*NCOL + col0 + t, g1, b1, xn_s, t);
  // in-wave read-back of own wave's columns
  FragU bx[4][2];
  #pragma unroll
  for (int nt = 0; nt < 4; nt++)
    #pragma unroll
    for (int ks = 0; ks < 2; ks++)
      bx[nt][ks].q = *(const u32x4*)(xn_s + ((4*w+nt)*16 + l16)*72 + ks*32 + qq*8);
  __syncthreads();   // barrier 1: xn dead; O_s/Mg_s may overwrite

  // ---- Mg build: O = sum of 16 slices; Mg = wout @ ctx / Z ----
  {
    const float* Ob = O16 + (long)b*16*4096;
    #pragma unroll
    for (int j = 0; j < 4; j++){
      floatx4 a = floatx4{0.f,0.f,0.f,0.f};
      #pragma unroll
      for (int s16 = 0; s16 < 16; s16++)
        a += ((const floatx4*)(Ob + s16*4096))[j*256 + t];
      ((floatx4*)O_s)[j*256 + t] = a;
    }
    __syncthreads();   // barrier 2: O_s complete (also sp visible)

    const int h = t >> 6, o = t & 63;            // wave h computes head h's 64 rows
    float wrow[32];
    #pragma unroll
    for (int ee = 0; ee < 32; ee++) wrow[ee] = wout[o*128 + h*32 + ee];
    #pragma unroll
    for (int j2 = 0; j2 < 16; j2++){
      float m01[2];
      #pragma unroll
      for (int half = 0; half < 2; half++){
        const int dd = j2*2 + half;
        const int dt = dd >> 4, qq2 = (dd >> 2) & 3, rg2 = dd & 3;
        float m = 0.f;
        #pragma unroll
        for (int ee = 0; ee < 32; ee++){
          const int et = ee >> 4, l16e = ee & 15;
          m = fmaf(wrow[ee], O_s[h*1024 + (dt*2+et)*256 + (qq2*16+l16e)*4 + rg2], m);
        }
        m01[half] = m / Zg[b*128 + h*32 + dd];
      }
      // wave-private rows of Mg_s (wave h owns [h*64, h*64+64)) -> in-wave DS ordering
      *(unsigned*)(Mg_s + (h*64 + o)*32 + j2*2) =
          (unsigned)bfb(m01[0]) | ((unsigned)bfb(m01[1]) << 16);
    }
  }
  __syncthreads();   // barrier 3: Mg_s ready for all waves; O_s dead (qs may overwrite)

  floatx4 yacc[4][4];
  #pragma unroll
  for (int ot = 0; ot < 4; ot++)
    #pragma unroll
    for (int nt = 0; nt < 4; nt++)
      yacc[ot][nt] = floatx4{0.f,0.f,0.f,0.f};

  #pragma unroll
  for (int h = 0; h < 4; h++){
    // q GEMM -> exp -> in-register column softmax (shfl over qq lanes) -> qs_s
    FragU a00, a01, a10, a11;
    {
      const unsigned short* wr0 = wbf + (h*32 + l16)*64 + qq*8;
      const unsigned short* wr1 = wbf + (h*32 + 16 + l16)*64 + qq*8;
      a00.q = *(const u32x4*)wr0; a01.q = *(const u32x4*)(wr0 + 32);
      a10.q = *(const u32x4*)wr1; a11.q = *(const u32x4*)(wr1 + 32);
    }
    #pragma unroll
    for (int nt = 0; nt < 4; nt++){
      floatx4 c0 = floatx4{0.f,0.f,0.f,0.f};
      floatx4 c1 = floatx4{0.f,0.f,0.f,0.f};
      c0 = __builtin_amdgcn_mfma_f32_16x16x32_bf16(a00.v, bx[nt][0].v, c0, 0, 0, 0);
      c0 = __builtin_amdgcn_mfma_f32_16x16x32_bf16(a01.v, bx[nt][1].v, c0, 0, 0, 0);
      c1 = __builtin_amdgcn_mfma_f32_16x16x32_bf16(a10.v, bx[nt][0].v, c1, 0, 0, 0);
      c1 = __builtin_amdgcn_mfma_f32_16x16x32_bf16(a11.v, bx[nt][1].v, c1, 0, 0, 0);
      float e[8]; float s = 0.f;
      #pragma unroll
      for (int r = 0; r < 4; r++){ e[r] = __expf(c0[r]); s += e[r]; }
      #pragma unroll
      for (int r = 0; r < 4; r++){ e[4+r] = __expf(c1[r]); s += e[4+r]; }
      // column (4w+nt)*16+l16 spans lanes {l16, l16+16, l16+32, l16+48}
      s += __shfl_xor(s, 16, 64); s += __shfl_xor(s, 32, 64);
      const float sc = 0.17677669529663687f / s;   // 32^-0.5 / sum
      const int colb = (4*w+nt)*16 + l16;
      u32x2 pk0, pk1;
      pk0[0] = (unsigned)bfb(e[0]*sc) | ((unsigned)bfb(e[1]*sc) << 16);
      pk0[1] = (unsigned)bfb(e[2]*sc) | ((unsigned)bfb(e[3]*sc) << 16);
      pk1[0] = (unsigned)bfb(e[4]*sc) | ((unsigned)bfb(e[5]*sc) << 16);
      pk1[1] = (unsigned)bfb(e[6]*sc) | ((unsigned)bfb(e[7]*sc) << 16);
      *(u32x2*)(qs_s + colb*40 + qq*4)      = pk0;
      *(u32x2*)(qs_s + colb*40 + 16 + qq*4) = pk1;
    }
    // y += M_h @ qs_h  (in-wave DS ordering: qs writes above precede these reads)
    #pragma unroll
    for (int ot = 0; ot < 4; ot++){
      FragU am;
      am.q = *(const u32x4*)(Mg_s + (h*64 + ot*16 + l16)*32 + qq*8);
      #pragma unroll
      for (int nt = 0; nt < 4; nt++){
        FragU bq; bq.q = *(const u32x4*)(qs_s + ((4*w+nt)*16 + l16)*40 + qq*8);
        yacc[ot][nt] = __builtin_amdgcn_mfma_f32_16x16x32_bf16(am.v, bq.v, yacc[ot][nt], 0, 0, 0);
      }
    }
  }

  // epilogue: +b_out, LN2 over 64 rows (rows live on lanes {l16, l16+16, l16+32, l16+48})
  const long ybase = (long)b*CH*NCOL;
  #pragma unroll
  for (int nt = 0; nt < 4; nt++){
    const long colg = col0 + (4*w+nt)*16 + l16;
    float vals[16]; float s = 0.f, ss = 0.f;
    #pragma unroll
    for (int ot = 0; ot < 4; ot++)
      #pragma unroll
      for (int r = 0; r < 4; r++){
        const float v = yacc[ot][nt][r] + sp[ot*16 + qq*4 + r];
        vals[ot*4+r] = v; s += v; ss = fmaf(v, v, ss);
      }
    s  += __shfl_xor(s, 16, 64);  s  += __shfl_xor(s, 32, 64);
    ss += __shfl_xor(ss, 16, 64); ss += __shfl_xor(ss, 32, 64);
    const float mean = s * (1.f/64.f);
    const float rstd = rsqrtf(ss * (1.f/64.f) - mean*mean + 1e-5f);
    #pragma unroll
    for (int ot = 0; ot < 4; ot++)
      #pragma unroll
      for (int r = 0; r < 4; r++){
        const int row = ot*16 + qq*4 + r;
        y[ybase + (long)row*NCOL + colg] = (vals[ot*4+r]-mean)*rstd*sp[64+row] + sp[128+row];
      }
  }
}

extern "C" void kernel_launch(void* const* d_in, const int* in_sizes, int n_in,
                              void* d_out, int out_size, void* d_ws, size_t ws_size,
                              hipStream_t stream)
{
  const float* x    = (const float*)d_in[0];
  const float* g1   = (const float*)d_in[1];
  const float* b1   = (const float*)d_in[2];
  const float* wqkv = (const float*)d_in[3];
  const float* wout = (const float*)d_in[4];
  const float* bout = (const float*)d_in[5];
  const float* g2   = (const float*)d_in[6];
  const float* b2   = (const float*)d_in[7];
  float* y  = (float*)d_out;
  float* ws = (float*)d_ws;

  float* O16 = ws;                                        // [0, 131072)  2 x 16 x 4096 (zeroed by kW)
  float* Zg  = ws + 131072;                               // [131072, 131328) (zeroed by kW)
  unsigned short* wbf = (unsigned short*)(ws + 131328);   // 24576 shorts -> ends 143616 fl

  hipLaunchKernelGGL(kW, dim3(516),  dim3(256), 0, stream, wqkv, wbf, O16);
  hipLaunchKernelGGL(kA, dim3(1024), dim3(256), 0, stream, x, g1, b1, wbf, O16, Zg);
  hipLaunchKernelGGL(kB, dim3(1024), dim3(256), 0, stream, x, g1, b1, wbf, O16, Zg, wout, bout, g2, b2, y);
}

// Round 10
// 237.604 us; speedup vs baseline: 2.3424x; 2.3424x over previous
//
#include <hip/hip_runtime.h>

// LinearAttention fused, MFMA (bf16 in / fp32 acc). 4-kernel pipeline, r4-derived.
//   kW : zero O/Zg + pre-convert w_qkv (384x64) -> bf16
//   kA : EXACT round-4 kA (best codegen observed: no spill) + optional xn->global
//        store (guarded by pointer; enables kB slim front).
//   kR1: EXACT round-4 reduce: pctx -> O (8-way atomic contention).
//   kB : r4 h-loop/epilogue + folded Mg build (from r9, verified). Two variants:
//        kBf = r4 LN front (safe);  kBs = bx loaded from cached xn (no LN, no xv[64]).
//   Host branches on ws_size: if workspace fits xng (50.4MB) use kA(store)+kBs.
//   Reduction-cost hierarchy measured this session:
//     LDS staged reduce (r4, good) << pctx store+re-read << global atomics (r9: 443us).
#define NCOL 131072
#define CH 64

typedef float floatx4 __attribute__((ext_vector_type(4)));
typedef __bf16 bf16x8 __attribute__((ext_vector_type(8)));
typedef unsigned int u32x4 __attribute__((ext_vector_type(4)));
typedef unsigned int u32x2 __attribute__((ext_vector_type(2)));

union FragU { u32x4 q; bf16x8 v; unsigned short us[8]; };

__device__ __forceinline__ unsigned short bfb(float f){
  union { __bf16 h; unsigned short s; } u; u.h = (__bf16)f; return u.s;
}
__device__ __forceinline__ float bf2f(unsigned short h){
  union { unsigned u; float f; } x{(unsigned)h << 16};
  return x.f;
}

// LN over 64 channels for column (thread t) -> bf16 column at xn_s[t][0..63] (stride 72).
// If xg != null, also mirror the column to global (contiguous 128B per thread).
__device__ __forceinline__ void ln_stage(const float* __restrict__ xp,
    const float* __restrict__ g, const float* __restrict__ bb,
    unsigned short* __restrict__ xn_s, int t, unsigned short* __restrict__ xg)
{
  float xv[64]; float s = 0.f, ss = 0.f;
  #pragma unroll
  for (int c = 0; c < 64; c++){ float u = xp[(long)c*NCOL]; xv[c] = u; s += u; ss = fmaf(u,u,ss); }
  const float mean = s * (1.f/64.f);
  const float rstd = rsqrtf(ss * (1.f/64.f) - mean*mean + 1e-5f);
  #pragma unroll
  for (int c = 0; c < 64; c++) xv[c] = (xv[c]-mean)*rstd*g[c] + bb[c];
  #pragma unroll
  for (int j = 0; j < 8; j++){
    FragU u;
    #pragma unroll
    for (int e = 0; e < 8; e++) u.v[e] = (__bf16)xv[j*8+e];
    *(u32x4*)(xn_s + t*72 + j*8) = u.q;
    if (xg) *(u32x4*)(xg + j*8) = u.q;
  }
}

// ---------------- kW: zero O+Zg, convert wqkv -> bf16 ----------------
__global__ __launch_bounds__(256) void kW(
    const float* __restrict__ wqkv, unsigned short* __restrict__ wbf, float* __restrict__ Oz)
{
  const int i = blockIdx.x*256 + threadIdx.x;   // grid 96 -> 24576 threads
  wbf[i] = bfb(wqkv[i]);                        // 384*64
  if (i < 8448) Oz[i] = 0.f;                    // O (8192) + Zg (256)
}

// ---------------- kA (round-4 body + optional xn mirror) ----------------
__global__ __launch_bounds__(256) void kA(
    const float* __restrict__ x, const float* __restrict__ g1, const float* __restrict__ b1,
    const unsigned short* __restrict__ wbf, float* __restrict__ pctx, float* __restrict__ Zg,
    unsigned short* __restrict__ xng)
{
  __shared__ __align__(16) char smem[37888];
  unsigned short* xn_s = (unsigned short*)smem;             // [0,36864) staging (dead after bx)
  unsigned short* ek_s = (unsigned short*)smem;             // [0,16896)   alias
  unsigned short* v_s  = (unsigned short*)(smem + 16896);   // [16896,33792) alias
  float* Zp            = (float*)(smem + 33792);            // [33792,35840) : [w][128]

  const int t = threadIdx.x;
  const int bid = blockIdx.x;
  const int b = bid >> 9;
  const long col0 = (long)(bid & 511) * 256;
  const int w = t >> 6, lane = t & 63, qq = lane >> 4, l16 = lane & 15;

  ln_stage(x + (long)b*CH*NCOL + col0 + t, g1, b1, xn_s, t,
           xng ? xng + ((long)b*NCOL + col0 + t)*64 : (unsigned short*)nullptr);
  // in-wave read-back of own wave's columns (DS in-order per wave; no barrier)
  FragU bx[4][2];
  #pragma unroll
  for (int nt = 0; nt < 4; nt++)
    #pragma unroll
    for (int ks = 0; ks < 2; ks++)
      bx[nt][ks].q = *(const u32x4*)(xn_s + ((4*w+nt)*16 + l16)*72 + ks*32 + qq*8);
  __syncthreads();   // alias guard: all waves' bx loaded before ek/v overwrite xn

  floatx4 cc[4][2][2];
  #pragma unroll
  for (int h = 0; h < 4; h++)
    #pragma unroll
    for (int dt = 0; dt < 2; dt++)
      #pragma unroll
      for (int et = 0; et < 2; et++)
        cc[h][dt][et] = floatx4{0.f,0.f,0.f,0.f};

  #pragma unroll
  for (int h = 0; h < 4; h++){
    float zr[8];
    #pragma unroll
    for (int j = 0; j < 8; j++) zr[j] = 0.f;
    // k (rt 0,1) and v (rt 2,3) GEMM, 16 rows per rt; wave-private column slices
    #pragma unroll
    for (int rt = 0; rt < 4; rt++){
      const int row0 = ((rt < 2) ? 128 : 256) + h*32 + (rt & 1)*16;
      const unsigned short* wr = wbf + (row0 + l16)*64 + qq*8;
      FragU a0, a1;
      a0.q = *(const u32x4*)wr;
      a1.q = *(const u32x4*)(wr + 32);
      unsigned short* dst = ((rt < 2) ? ek_s : v_s) + ((rt & 1)*16 + qq*4)*264;
      #pragma unroll
      for (int nt = 0; nt < 4; nt++){
        floatx4 c = floatx4{0.f,0.f,0.f,0.f};
        c = __builtin_amdgcn_mfma_f32_16x16x32_bf16(a0.v, bx[nt][0].v, c, 0, 0, 0);
        c = __builtin_amdgcn_mfma_f32_16x16x32_bf16(a1.v, bx[nt][1].v, c, 0, 0, 0);
        const int colb = (4*w+nt)*16 + l16;
        if (rt < 2){
          #pragma unroll
          for (int r = 0; r < 4; r++){
            const float e = __expf(c[r]);
            dst[r*264 + colb] = bfb(e);
            zr[(rt & 1)*4 + r] += e;
          }
        } else {
          #pragma unroll
          for (int r = 0; r < 4; r++) dst[r*264 + colb] = bfb(c[r]);
        }
      }
    }
    // Z partial for this wave's 64 cols: butterfly over l16 lanes
    #pragma unroll
    for (int j = 0; j < 8; j++){
      float v = zr[j];
      v += __shfl_xor(v, 1, 64); v += __shfl_xor(v, 2, 64);
      v += __shfl_xor(v, 4, 64); v += __shfl_xor(v, 8, 64);
      if (l16 == 0) Zp[w*128 + h*32 + (j >> 2)*16 + qq*4 + (j & 3)] = v;
    }
    // ctx MFMAs: wave w covers its own cols [64w,64w+64); in-wave DS ordering
    #pragma unroll
    for (int kk = 0; kk < 2; kk++){
      const int ks2 = 2*w + kk;
      FragU ae[2], bv[2];
      #pragma unroll
      for (int dt = 0; dt < 2; dt++) ae[dt].q = *(const u32x4*)(ek_s + (dt*16 + l16)*264 + ks2*32 + qq*8);
      #pragma unroll
      for (int et = 0; et < 2; et++) bv[et].q = *(const u32x4*)(v_s + (et*16 + l16)*264 + ks2*32 + qq*8);
      #pragma unroll
      for (int dt = 0; dt < 2; dt++)
        #pragma unroll
        for (int et = 0; et < 2; et++)
          cc[h][dt][et] = __builtin_amdgcn_mfma_f32_16x16x32_bf16(ae[dt].v, bv[et].v, cc[h][dt][et], 0, 0, 0);
    }
  }
  __syncthreads();   // all waves done with ek/v and Zp writes

  if (t < 128){
    const float z = Zp[t] + Zp[128 + t] + Zp[256 + t] + Zp[384 + t];
    atomicAdd(&Zg[b*128 + t], z);   // t == h*32+d
  }

  // cross-wave ctx reduction, staged in 32 KiB (scr aliases ek_s/v_s; Zp untouched)
  float* scr = (float*)smem;
  if (w & 1){
    #pragma unroll
    for (int h = 0; h < 4; h++)
      #pragma unroll
      for (int dt = 0; dt < 2; dt++)
        #pragma unroll
        for (int et = 0; et < 2; et++)
          ((floatx4*)scr)[(w>>1)*1024 + (h*4 + dt*2 + et)*64 + lane] = cc[h][dt][et];
  }
  __syncthreads();
  if (!(w & 1)){
    #pragma unroll
    for (int h = 0; h < 4; h++)
      #pragma unroll
      for (int dt = 0; dt < 2; dt++)
        #pragma unroll
        for (int et = 0; et < 2; et++)
          cc[h][dt][et] += ((floatx4*)scr)[(w>>1)*1024 + (h*4 + dt*2 + et)*64 + lane];
  }
  __syncthreads();
  if (w == 2){
    #pragma unroll
    for (int h = 0; h < 4; h++)
      #pragma unroll
      for (int dt = 0; dt < 2; dt++)
        #pragma unroll
        for (int et = 0; et < 2; et++)
          ((floatx4*)scr)[(h*4 + dt*2 + et)*64 + lane] = cc[h][dt][et];
  }
  __syncthreads();
  if (w == 0){
    #pragma unroll
    for (int h = 0; h < 4; h++)
      #pragma unroll
      for (int dt = 0; dt < 2; dt++)
        #pragma unroll
        for (int et = 0; et < 2; et++){
          floatx4 r = cc[h][dt][et] + ((floatx4*)scr)[(h*4 + dt*2 + et)*64 + lane];
          *(floatx4*)(pctx + (long)bid*4096 + (h*4 + dt*2 + et)*256 + lane*4) = r;
        }
  }
}

// ---------------- kR1: coalesced partial reduction -> atomic accumulate (r4 exact) ----------------
__global__ __launch_bounds__(256) void kR1(
    const float* __restrict__ pctx, float* __restrict__ O)
{
  const int blk = blockIdx.x;          // 256 blocks
  const int b = blk >> 7;              // 0..1
  const int part = (blk >> 4) & 7;     // 0..7   (64 pctx rows each)
  const int chunk = blk & 15;          // 0..15  (256 r-columns each)
  const int t = threadIdx.x;
  const int r = chunk*256 + t;
  const float* p = pctx + ((long)(b*512 + part*64))*4096 + r;
  float s = 0.f;
  #pragma unroll 16
  for (int row = 0; row < 64; row++) s += p[(long)row*4096];
  atomicAdd(&O[b*4096 + r], s);        // 8-way contention per location
}

// ---------------- shared kB body: Mg build + h-loop + epilogue ----------------
__device__ __forceinline__ void kB_body(
    const unsigned short* __restrict__ wbf, const float* __restrict__ O,
    const float* __restrict__ Zg, const float* __restrict__ wout,
    float* __restrict__ y, char* smem, const FragU bx[4][2],
    int t, int b, long col0, int w, int lane, int qq, int l16)
{
  float* O_s           = (float*)smem;                      // [0,16384)  (Mg phase)
  unsigned short* qs_s = (unsigned short*)smem;             // [0,20480)  alias (h-loop)
  unsigned short* Mg_s = (unsigned short*)(smem + 20480);   // [20480,36864)
  float* sp            = (float*)(smem + 36864);            // 192 floats

  // ---- Mg build (was kM): O[b] -> LDS; Mg = wout @ ctx / Z ----
  {
    const float* Ob = O + (long)b*4096;
    #pragma unroll
    for (int j = 0; j < 4; j++)
      ((floatx4*)O_s)[j*256 + t] = ((const floatx4*)Ob)[j*256 + t];
    __syncthreads();   // O_s complete (also sp visible)

    const int h = t >> 6, o = t & 63;            // wave h computes head h's 64 rows
    float wrow[32];
    #pragma unroll
    for (int ee = 0; ee < 32; ee++) wrow[ee] = wout[o*128 + h*32 + ee];
    #pragma unroll
    for (int j2 = 0; j2 < 16; j2++){
      float m01[2];
      #pragma unroll
      for (int half = 0; half < 2; half++){
        const int dd = j2*2 + half;
        const int dt = dd >> 4, qq2 = (dd >> 2) & 3, rg2 = dd & 3;
        float m = 0.f;
        #pragma unroll
        for (int ee = 0; ee < 32; ee++){
          const int et = ee >> 4, l16e = ee & 15;
          m = fmaf(wrow[ee], O_s[h*1024 + (dt*2+et)*256 + (qq2*16+l16e)*4 + rg2], m);
        }
        m01[half] = m / Zg[b*128 + h*32 + dd];
      }
      *(unsigned*)(Mg_s + (h*64 + o)*32 + j2*2) =
          (unsigned)bfb(m01[0]) | ((unsigned)bfb(m01[1]) << 16);
    }
  }
  __syncthreads();   // Mg_s ready for all waves; O_s dead (qs may overwrite)

  floatx4 yacc[4][4];
  #pragma unroll
  for (int ot = 0; ot < 4; ot++)
    #pragma unroll
    for (int nt = 0; nt < 4; nt++)
      yacc[ot][nt] = floatx4{0.f,0.f,0.f,0.f};

  #pragma unroll
  for (int h = 0; h < 4; h++){
    // q GEMM -> exp -> in-register column softmax (shfl over qq lanes) -> qs_s
    FragU a00, a01, a10, a11;
    {
      const unsigned short* wr0 = wbf + (h*32 + l16)*64 + qq*8;
      const unsigned short* wr1 = wbf + (h*32 + 16 + l16)*64 + qq*8;
      a00.q = *(const u32x4*)wr0; a01.q = *(const u32x4*)(wr0 + 32);
      a10.q = *(const u32x4*)wr1; a11.q = *(const u32x4*)(wr1 + 32);
    }
    #pragma unroll
    for (int nt = 0; nt < 4; nt++){
      floatx4 c0 = floatx4{0.f,0.f,0.f,0.f};
      floatx4 c1 = floatx4{0.f,0.f,0.f,0.f};
      c0 = __builtin_amdgcn_mfma_f32_16x16x32_bf16(a00.v, bx[nt][0].v, c0, 0, 0, 0);
      c0 = __builtin_amdgcn_mfma_f32_16x16x32_bf16(a01.v, bx[nt][1].v, c0, 0, 0, 0);
      c1 = __builtin_amdgcn_mfma_f32_16x16x32_bf16(a10.v, bx[nt][0].v, c1, 0, 0, 0);
      c1 = __builtin_amdgcn_mfma_f32_16x16x32_bf16(a11.v, bx[nt][1].v, c1, 0, 0, 0);
      float e[8]; float s = 0.f;
      #pragma unroll
      for (int r = 0; r < 4; r++){ e[r] = __expf(c0[r]); s += e[r]; }
      #pragma unroll
      for (int r = 0; r < 4; r++){ e[4+r] = __expf(c1[r]); s += e[4+r]; }
      s += __shfl_xor(s, 16, 64); s += __shfl_xor(s, 32, 64);
      const float sc = 0.17677669529663687f / s;   // 32^-0.5 / sum
      const int colb = (4*w+nt)*16 + l16;
      u32x2 pk0, pk1;
      pk0[0] = (unsigned)bfb(e[0]*sc) | ((unsigned)bfb(e[1]*sc) << 16);
      pk0[1] = (unsigned)bfb(e[2]*sc) | ((unsigned)bfb(e[3]*sc) << 16);
      pk1[0] = (unsigned)bfb(e[4]*sc) | ((unsigned)bfb(e[5]*sc) << 16);
      pk1[1] = (unsigned)bfb(e[6]*sc) | ((unsigned)bfb(e[7]*sc) << 16);
      *(u32x2*)(qs_s + colb*40 + qq*4)      = pk0;
      *(u32x2*)(qs_s + colb*40 + 16 + qq*4) = pk1;
    }
    // y += M_h @ qs_h  (in-wave DS ordering)
    #pragma unroll
    for (int ot = 0; ot < 4; ot++){
      FragU am;
      am.q = *(const u32x4*)(Mg_s + (h*64 + ot*16 + l16)*32 + qq*8);
      #pragma unroll
      for (int nt = 0; nt < 4; nt++){
        FragU bq; bq.q = *(const u32x4*)(qs_s + ((4*w+nt)*16 + l16)*40 + qq*8);
        yacc[ot][nt] = __builtin_amdgcn_mfma_f32_16x16x32_bf16(am.v, bq.v, yacc[ot][nt], 0, 0, 0);
      }
    }
  }

  // epilogue: +b_out, LN2 over 64 rows
  const long ybase = (long)b*CH*NCOL;
  #pragma unroll
  for (int nt = 0; nt < 4; nt++){
    const long colg = col0 + (4*w+nt)*16 + l16;
    float vals[16]; float s = 0.f, ss = 0.f;
    #pragma unroll
    for (int ot = 0; ot < 4; ot++)
      #pragma unroll
      for (int r = 0; r < 4; r++){
        const float v = yacc[ot][nt][r] + sp[ot*16 + qq*4 + r];
        vals[ot*4+r] = v; s += v; ss = fmaf(v, v, ss);
      }
    s  += __shfl_xor(s, 16, 64);  s  += __shfl_xor(s, 32, 64);
    ss += __shfl_xor(ss, 16, 64); ss += __shfl_xor(ss, 32, 64);
    const float mean = s * (1.f/64.f);
    const float rstd = rsqrtf(ss * (1.f/64.f) - mean*mean + 1e-5f);
    #pragma unroll
    for (int ot = 0; ot < 4; ot++)
      #pragma unroll
      for (int r = 0; r < 4; r++){
        const int row = ot*16 + qq*4 + r;
        y[ybase + (long)row*NCOL + colg] = (vals[ot*4+r]-mean)*rstd*sp[64+row] + sp[128+row];
      }
  }
}

// ---------------- kBf: fat front (LN recompute, r4 path) ----------------
__global__ __launch_bounds__(256) void kBf(
    const float* __restrict__ x, const float* __restrict__ g1, const float* __restrict__ b1,
    const unsigned short* __restrict__ wbf, const float* __restrict__ O,
    const float* __restrict__ Zg, const float* __restrict__ wout,
    const float* __restrict__ bout, const float* __restrict__ g2, const float* __restrict__ b2,
    float* __restrict__ y)
{
  __shared__ __align__(16) char smem[37632];
  unsigned short* xn_s = (unsigned short*)smem;             // [0,36864) staging (dead after bx)
  float* sp            = (float*)(smem + 36864);

  const int t = threadIdx.x;
  const int bid = blockIdx.x;
  const int b = bid >> 9;
  const long col0 = (long)(bid & 511) * 256;
  const int w = t >> 6, lane = t & 63, qq = lane >> 4, l16 = lane & 15;

  if (t < 64){ sp[t] = bout[t]; sp[64+t] = g2[t]; sp[128+t] = b2[t]; }
  ln_stage(x + (long)b*CH*NCOL + col0 + t, g1, b1, xn_s, t, (unsigned short*)nullptr);
  FragU bx[4][2];
  #pragma unroll
  for (int nt = 0; nt < 4; nt++)
    #pragma unroll
    for (int ks = 0; ks < 2; ks++)
      bx[nt][ks].q = *(const u32x4*)(xn_s + ((4*w+nt)*16 + l16)*72 + ks*32 + qq*8);
  __syncthreads();   // xn dead; O_s/Mg_s may overwrite

  kB_body(wbf, O, Zg, wout, y, smem, bx, t, b, col0, w, lane, qq, l16);
}

// ---------------- kBs: slim front (bx from cached xn; no LN, no xv[64]) ----------------
__global__ __launch_bounds__(256) void kBs(
    const unsigned short* __restrict__ xng,
    const unsigned short* __restrict__ wbf, const float* __restrict__ O,
    const float* __restrict__ Zg, const float* __restrict__ wout,
    const float* __restrict__ bout, const float* __restrict__ g2, const float* __restrict__ b2,
    float* __restrict__ y)
{
  __shared__ __align__(16) char smem[37632];
  float* sp = (float*)(smem + 36864);

  const int t = threadIdx.x;
  const int bid = blockIdx.x;
  const int b = bid >> 9;
  const long col0 = (long)(bid & 511) * 256;
  const int w = t >> 6, lane = t & 63, qq = lane >> 4, l16 = lane & 15;

  if (t < 64){ sp[t] = bout[t]; sp[64+t] = g2[t]; sp[128+t] = b2[t]; }
  FragU bx[4][2];
  #pragma unroll
  for (int nt = 0; nt < 4; nt++){
    const unsigned short* xr = xng + ((long)b*NCOL + col0 + (4*w+nt)*16 + l16)*64;
    #pragma unroll
    for (int ks = 0; ks < 2; ks++)
      bx[nt][ks].q = *(const u32x4*)(xr + ks*32 + qq*8);
  }
  // no barrier needed here: nothing has used region0 yet; kB_body's first barrier
  // (after O_s fill) provides sp visibility before any sp read.

  kB_body(wbf, O, Zg, wout, y, smem, bx, t, b, col0, w, lane, qq, l16);
}

extern "C" void kernel_launch(void* const* d_in, const int* in_sizes, int n_in,
                              void* d_out, int out_size, void* d_ws, size_t ws_size,
                              hipStream_t stream)
{
  const float* x    = (const float*)d_in[0];
  const float* g1   = (const float*)d_in[1];
  const float* b1   = (const float*)d_in[2];
  const float* wqkv = (const float*)d_in[3];
  const float* wout = (const float*)d_in[4];
  const float* bout = (const float*)d_in[5];
  const float* g2   = (const float*)d_in[6];
  const float* b2   = (const float*)d_in[7];
  float* y  = (float*)d_out;
  float* ws = (float*)d_ws;

  float* pctx = ws;                                        // [0, 4194304)
  float* O    = ws + 4194304;                              // 8192   (zeroed by kW)
  float* Zg   = ws + 4202496;                              // 256    (zeroed by kW)
  unsigned short* wbf = (unsigned short*)(ws + 4202752);   // 24576 shorts -> ends 4215040 fl
  unsigned short* xng = (unsigned short*)(ws + 4215040);   // 16777216 shorts -> ends 12603648 fl
  const bool big = ws_size >= (size_t)12603648 * 4;        // room for xng?

  hipLaunchKernelGGL(kW,  dim3(96),   dim3(256), 0, stream, wqkv, wbf, O);
  hipLaunchKernelGGL(kA,  dim3(1024), dim3(256), 0, stream, x, g1, b1, wbf, pctx, Zg,
                     big ? xng : (unsigned short*)nullptr);
  hipLaunchKernelGGL(kR1, dim3(256),  dim3(256), 0, stream, pctx, O);
  if (big)
    hipLaunchKernelGGL(kBs, dim3(1024), dim3(256), 0, stream, xng, wbf, O, Zg, wout, bout, g2, b2, y);
  else
    hipLaunchKernelGGL(kBf, dim3(1024), dim3(256), 0, stream, x, g1, b1, wbf, O, Zg, wout, bout, g2, b2, y);
}

// Round 11
// 216.177 us; speedup vs baseline: 2.5746x; 1.0991x over previous
//
#include <hip/hip_runtime.h>

// LinearAttention fused, MFMA (bf16 in / fp32 acc). 5-kernel pipeline, r4-derived.
//   kW : zero O/Zg + pre-convert w_qkv (384x64) -> bf16
//   kA : LN1 -> bx regs -> q GEMM+softmax -> qsg (NEW, before cc init: live regs low)
//        -> k,v GEMM -> exp(k) -> ctx partials -> pctx ; Z -> Zg. r4-exact otherwise.
//   kR1: pctx -> O (r4 exact).
//   kM : Mg = wout @ ctx / Z -> bf16 Mgbf (r4 exact; computed ONCE — r10's fold made
//        every kB block recompute it 512x redundantly: +10us, bank confl 0.9M->1.4M).
//   kC : stage Mg (16KB LDS) -> y = Mg @ qs (qs from global) -> +b_out -> LN2.
//        No LN, no exp, no softmax: x read once per element in the whole pipeline.
#define NCOL 131072
#define CH 64

typedef float floatx4 __attribute__((ext_vector_type(4)));
typedef __bf16 bf16x8 __attribute__((ext_vector_type(8)));
typedef unsigned int u32x4 __attribute__((ext_vector_type(4)));
typedef unsigned int u32x2 __attribute__((ext_vector_type(2)));

union FragU { u32x4 q; bf16x8 v; unsigned short us[8]; };

__device__ __forceinline__ unsigned short bfb(float f){
  union { __bf16 h; unsigned short s; } u; u.h = (__bf16)f; return u.s;
}
__device__ __forceinline__ float bf2f(unsigned short h){
  union { unsigned u; float f; } x{(unsigned)h << 16};
  return x.f;
}

// LN over 64 channels for column (thread t) -> bf16 column at xn_s[t][0..63] (stride 72).
__device__ __forceinline__ void ln_stage(const float* __restrict__ xp,
    const float* __restrict__ g, const float* __restrict__ bb,
    unsigned short* __restrict__ xn_s, int t)
{
  float xv[64]; float s = 0.f, ss = 0.f;
  #pragma unroll
  for (int c = 0; c < 64; c++){ float u = xp[(long)c*NCOL]; xv[c] = u; s += u; ss = fmaf(u,u,ss); }
  const float mean = s * (1.f/64.f);
  const float rstd = rsqrtf(ss * (1.f/64.f) - mean*mean + 1e-5f);
  #pragma unroll
  for (int c = 0; c < 64; c++) xv[c] = (xv[c]-mean)*rstd*g[c] + bb[c];
  #pragma unroll
  for (int j = 0; j < 8; j++){
    FragU u;
    #pragma unroll
    for (int e = 0; e < 8; e++) u.v[e] = (__bf16)xv[j*8+e];
    *(u32x4*)(xn_s + t*72 + j*8) = u.q;
  }
}

// ---------------- kW: zero O+Zg, convert wqkv -> bf16 ----------------
__global__ __launch_bounds__(256) void kW(
    const float* __restrict__ wqkv, unsigned short* __restrict__ wbf, float* __restrict__ Oz)
{
  const int i = blockIdx.x*256 + threadIdx.x;   // grid 96 -> 24576 threads
  wbf[i] = bfb(wqkv[i]);                        // 384*64
  if (i < 8448) Oz[i] = 0.f;                    // O (8192) + Zg (256)
}

// ---------------- kA ----------------
__global__ __launch_bounds__(256) void kA(
    const float* __restrict__ x, const float* __restrict__ g1, const float* __restrict__ b1,
    const unsigned short* __restrict__ wbf, float* __restrict__ pctx, float* __restrict__ Zg,
    unsigned short* __restrict__ qsg)
{
  __shared__ __align__(16) char smem[37888];
  unsigned short* xn_s = (unsigned short*)smem;             // [0,36864) staging (dead after bx)
  unsigned short* ek_s = (unsigned short*)smem;             // [0,16896)   alias
  unsigned short* v_s  = (unsigned short*)(smem + 16896);   // [16896,33792) alias
  float* Zp            = (float*)(smem + 33792);            // [33792,35840) : [w][128]

  const int t = threadIdx.x;
  const int bid = blockIdx.x;
  const int b = bid >> 9;
  const long col0 = (long)(bid & 511) * 256;
  const int w = t >> 6, lane = t & 63, qq = lane >> 4, l16 = lane & 15;

  ln_stage(x + (long)b*CH*NCOL + col0 + t, g1, b1, xn_s, t);
  // in-wave read-back of own wave's columns (DS in-order per wave; no barrier)
  FragU bx[4][2];
  #pragma unroll
  for (int nt = 0; nt < 4; nt++)
    #pragma unroll
    for (int ks = 0; ks < 2; ks++)
      bx[nt][ks].q = *(const u32x4*)(xn_s + ((4*w+nt)*16 + l16)*72 + ks*32 + qq*8);
  __syncthreads();   // alias guard: all waves' bx loaded before ek/v overwrite xn

  // ---- q GEMM -> exp -> column softmax (shfl) -> qsg store ----
  // Placed BEFORE cc init: live regs here = bx(32)+temps(~32), keeps r4's no-spill shape.
  #pragma unroll
  for (int h = 0; h < 4; h++){
    FragU a00, a01, a10, a11;
    {
      const unsigned short* wr0 = wbf + (h*32 + l16)*64 + qq*8;
      const unsigned short* wr1 = wbf + (h*32 + 16 + l16)*64 + qq*8;
      a00.q = *(const u32x4*)wr0; a01.q = *(const u32x4*)(wr0 + 32);
      a10.q = *(const u32x4*)wr1; a11.q = *(const u32x4*)(wr1 + 32);
    }
    #pragma unroll
    for (int nt = 0; nt < 4; nt++){
      floatx4 c0 = floatx4{0.f,0.f,0.f,0.f};
      floatx4 c1 = floatx4{0.f,0.f,0.f,0.f};
      c0 = __builtin_amdgcn_mfma_f32_16x16x32_bf16(a00.v, bx[nt][0].v, c0, 0, 0, 0);
      c0 = __builtin_amdgcn_mfma_f32_16x16x32_bf16(a01.v, bx[nt][1].v, c0, 0, 0, 0);
      c1 = __builtin_amdgcn_mfma_f32_16x16x32_bf16(a10.v, bx[nt][0].v, c1, 0, 0, 0);
      c1 = __builtin_amdgcn_mfma_f32_16x16x32_bf16(a11.v, bx[nt][1].v, c1, 0, 0, 0);
      float e[8]; float s = 0.f;
      #pragma unroll
      for (int r = 0; r < 4; r++){ e[r] = __expf(c0[r]); s += e[r]; }
      #pragma unroll
      for (int r = 0; r < 4; r++){ e[4+r] = __expf(c1[r]); s += e[4+r]; }
      // column (4w+nt)*16+l16 spans lanes {l16, l16+16, l16+32, l16+48}
      s += __shfl_xor(s, 16, 64); s += __shfl_xor(s, 32, 64);
      const float sc = 0.17677669529663687f / s;   // 32^-0.5 / sum
      const int colb = (4*w+nt)*16 + l16;
      unsigned short* qg = qsg + (((long)b*NCOL + col0 + colb)*32 + (long)h*NCOL*64);
      u32x2 pk0, pk1;
      pk0[0] = (unsigned)bfb(e[0]*sc) | ((unsigned)bfb(e[1]*sc) << 16);
      pk0[1] = (unsigned)bfb(e[2]*sc) | ((unsigned)bfb(e[3]*sc) << 16);
      pk1[0] = (unsigned)bfb(e[4]*sc) | ((unsigned)bfb(e[5]*sc) << 16);
      pk1[1] = (unsigned)bfb(e[6]*sc) | ((unsigned)bfb(e[7]*sc) << 16);
      *(u32x2*)(qg + qq*4)      = pk0;
      *(u32x2*)(qg + 16 + qq*4) = pk1;
    }
  }

  floatx4 cc[4][2][2];
  #pragma unroll
  for (int h = 0; h < 4; h++)
    #pragma unroll
    for (int dt = 0; dt < 2; dt++)
      #pragma unroll
      for (int et = 0; et < 2; et++)
        cc[h][dt][et] = floatx4{0.f,0.f,0.f,0.f};

  #pragma unroll
  for (int h = 0; h < 4; h++){
    float zr[8];
    #pragma unroll
    for (int j = 0; j < 8; j++) zr[j] = 0.f;
    // k (rt 0,1) and v (rt 2,3) GEMM, 16 rows per rt; wave-private column slices
    #pragma unroll
    for (int rt = 0; rt < 4; rt++){
      const int row0 = ((rt < 2) ? 128 : 256) + h*32 + (rt & 1)*16;
      const unsigned short* wr = wbf + (row0 + l16)*64 + qq*8;
      FragU a0, a1;
      a0.q = *(const u32x4*)wr;
      a1.q = *(const u32x4*)(wr + 32);
      unsigned short* dst = ((rt < 2) ? ek_s : v_s) + ((rt & 1)*16 + qq*4)*264;
      #pragma unroll
      for (int nt = 0; nt < 4; nt++){
        floatx4 c = floatx4{0.f,0.f,0.f,0.f};
        c = __builtin_amdgcn_mfma_f32_16x16x32_bf16(a0.v, bx[nt][0].v, c, 0, 0, 0);
        c = __builtin_amdgcn_mfma_f32_16x16x32_bf16(a1.v, bx[nt][1].v, c, 0, 0, 0);
        const int colb = (4*w+nt)*16 + l16;
        if (rt < 2){
          #pragma unroll
          for (int r = 0; r < 4; r++){
            const float e = __expf(c[r]);
            dst[r*264 + colb] = bfb(e);
            zr[(rt & 1)*4 + r] += e;
          }
        } else {
          #pragma unroll
          for (int r = 0; r < 4; r++) dst[r*264 + colb] = bfb(c[r]);
        }
      }
    }
    // Z partial for this wave's 64 cols: butterfly over l16 lanes
    #pragma unroll
    for (int j = 0; j < 8; j++){
      float v = zr[j];
      v += __shfl_xor(v, 1, 64); v += __shfl_xor(v, 2, 64);
      v += __shfl_xor(v, 4, 64); v += __shfl_xor(v, 8, 64);
      if (l16 == 0) Zp[w*128 + h*32 + (j >> 2)*16 + qq*4 + (j & 3)] = v;
    }
    // ctx MFMAs: wave w covers its own cols [64w,64w+64); in-wave DS ordering
    #pragma unroll
    for (int kk = 0; kk < 2; kk++){
      const int ks2 = 2*w + kk;
      FragU ae[2], bv[2];
      #pragma unroll
      for (int dt = 0; dt < 2; dt++) ae[dt].q = *(const u32x4*)(ek_s + (dt*16 + l16)*264 + ks2*32 + qq*8);
      #pragma unroll
      for (int et = 0; et < 2; et++) bv[et].q = *(const u32x4*)(v_s + (et*16 + l16)*264 + ks2*32 + qq*8);
      #pragma unroll
      for (int dt = 0; dt < 2; dt++)
        #pragma unroll
        for (int et = 0; et < 2; et++)
          cc[h][dt][et] = __builtin_amdgcn_mfma_f32_16x16x32_bf16(ae[dt].v, bv[et].v, cc[h][dt][et], 0, 0, 0);
    }
  }
  __syncthreads();   // all waves done with ek/v and Zp writes

  if (t < 128){
    const float z = Zp[t] + Zp[128 + t] + Zp[256 + t] + Zp[384 + t];
    atomicAdd(&Zg[b*128 + t], z);   // t == h*32+d
  }

  // cross-wave ctx reduction, staged in 32 KiB (scr aliases ek_s/v_s; Zp untouched)
  float* scr = (float*)smem;
  if (w & 1){
    #pragma unroll
    for (int h = 0; h < 4; h++)
      #pragma unroll
      for (int dt = 0; dt < 2; dt++)
        #pragma unroll
        for (int et = 0; et < 2; et++)
          ((floatx4*)scr)[(w>>1)*1024 + (h*4 + dt*2 + et)*64 + lane] = cc[h][dt][et];
  }
  __syncthreads();
  if (!(w & 1)){
    #pragma unroll
    for (int h = 0; h < 4; h++)
      #pragma unroll
      for (int dt = 0; dt < 2; dt++)
        #pragma unroll
        for (int et = 0; et < 2; et++)
          cc[h][dt][et] += ((floatx4*)scr)[(w>>1)*1024 + (h*4 + dt*2 + et)*64 + lane];
  }
  __syncthreads();
  if (w == 2){
    #pragma unroll
    for (int h = 0; h < 4; h++)
      #pragma unroll
      for (int dt = 0; dt < 2; dt++)
        #pragma unroll
        for (int et = 0; et < 2; et++)
          ((floatx4*)scr)[(h*4 + dt*2 + et)*64 + lane] = cc[h][dt][et];
  }
  __syncthreads();
  if (w == 0){
    #pragma unroll
    for (int h = 0; h < 4; h++)
      #pragma unroll
      for (int dt = 0; dt < 2; dt++)
        #pragma unroll
        for (int et = 0; et < 2; et++){
          floatx4 r = cc[h][dt][et] + ((floatx4*)scr)[(h*4 + dt*2 + et)*64 + lane];
          *(floatx4*)(pctx + (long)bid*4096 + (h*4 + dt*2 + et)*256 + lane*4) = r;
        }
  }
}

// ---------------- kR1: coalesced partial reduction -> atomic accumulate (r4 exact) ----------------
__global__ __launch_bounds__(256) void kR1(
    const float* __restrict__ pctx, float* __restrict__ O)
{
  const int blk = blockIdx.x;          // 256 blocks
  const int b = blk >> 7;              // 0..1
  const int part = (blk >> 4) & 7;     // 0..7   (64 pctx rows each)
  const int chunk = blk & 15;          // 0..15  (256 r-columns each)
  const int t = threadIdx.x;
  const int r = chunk*256 + t;
  const float* p = pctx + ((long)(b*512 + part*64))*4096 + r;
  float s = 0.f;
  #pragma unroll 16
  for (int row = 0; row < 64; row++) s += p[(long)row*4096];
  atomicAdd(&O[b*4096 + r], s);        // 8-way contention per location
}

// ---------------- kM: fuse w_out and 1/Z into ctx, emit bf16 (r4 exact) ----------------
__global__ __launch_bounds__(256) void kM(
    const float* __restrict__ O, const float* __restrict__ Zg,
    const float* __restrict__ wout, unsigned short* __restrict__ Mgbf)
{
  const int idx = blockIdx.x*256 + threadIdx.x;  // 0..16383
  const int b = idx >> 13, rem = idx & 8191;
  const int h = rem >> 11, o = (rem >> 5) & 63, dd = rem & 31;
  const int dt = dd >> 4, qq = (dd >> 2) & 3, rg = dd & 3;
  float m = 0.f;
  #pragma unroll
  for (int ee = 0; ee < 32; ee++){
    const int et = ee >> 4, l16 = ee & 15;
    const int r = h*1024 + (dt*2 + et)*256 + (qq*16 + l16)*4 + rg;
    m = fmaf(wout[o*128 + h*32 + ee], O[b*4096 + r], m);
  }
  m /= Zg[b*128 + h*32 + dd];
  Mgbf[idx] = bfb(m);                  // idx == ((b*4+h)*64+o)*32+dd
}

// ---------------- kC: y = Mg @ qs -> +b_out -> LN2 ----------------
__global__ __launch_bounds__(256) void kC(
    const unsigned short* __restrict__ qsg, const unsigned short* __restrict__ Mgbf,
    const float* __restrict__ bout, const float* __restrict__ g2, const float* __restrict__ b2,
    float* __restrict__ y)
{
  __shared__ __align__(16) char smem[17152];
  unsigned short* Mg_s = (unsigned short*)smem;   // [0,16384) : this batch's Mg (8192 shorts)
  float* sp            = (float*)(smem + 16384);  // 192 floats

  const int t = threadIdx.x;
  const int bid = blockIdx.x;
  const int b = bid >> 9;
  const long col0 = (long)(bid & 511) * 256;
  const int w = t >> 6, lane = t & 63, qq = lane >> 4, l16 = lane & 15;

  if (t < 64){ sp[t] = bout[t]; sp[64+t] = g2[t]; sp[128+t] = b2[t]; }
  // stage Mg[b]: 8192 shorts = 1024 x 16B, 256 threads x 4
  #pragma unroll
  for (int j = 0; j < 4; j++)
    ((u32x4*)Mg_s)[j*256 + t] = ((const u32x4*)(Mgbf + (long)b*8192))[j*256 + t];
  __syncthreads();   // Mg_s + sp ready (only barrier in kC)

  floatx4 yacc[4][4];
  #pragma unroll
  for (int ot = 0; ot < 4; ot++)
    #pragma unroll
    for (int nt = 0; nt < 4; nt++)
      yacc[ot][nt] = floatx4{0.f,0.f,0.f,0.f};

  #pragma unroll
  for (int h = 0; h < 4; h++){
    FragU bq[4];
    #pragma unroll
    for (int nt = 0; nt < 4; nt++)
      bq[nt].q = *(const u32x4*)(qsg + ((long)b*NCOL + col0 + (4*w+nt)*16 + l16)*32
                                      + (long)h*NCOL*64 + qq*8);
    #pragma unroll
    for (int ot = 0; ot < 4; ot++){
      FragU am;
      am.q = *(const u32x4*)(Mg_s + (h*64 + ot*16 + l16)*32 + qq*8);
      #pragma unroll
      for (int nt = 0; nt < 4; nt++)
        yacc[ot][nt] = __builtin_amdgcn_mfma_f32_16x16x32_bf16(am.v, bq[nt].v, yacc[ot][nt], 0, 0, 0);
    }
  }

  // epilogue: +b_out, LN2 over 64 rows (rows live on lanes {l16, l16+16, l16+32, l16+48})
  const long ybase = (long)b*CH*NCOL;
  #pragma unroll
  for (int nt = 0; nt < 4; nt++){
    const long colg = col0 + (4*w+nt)*16 + l16;
    float vals[16]; float s = 0.f, ss = 0.f;
    #pragma unroll
    for (int ot = 0; ot < 4; ot++)
      #pragma unroll
      for (int r = 0; r < 4; r++){
        const float v = yacc[ot][nt][r] + sp[ot*16 + qq*4 + r];
        vals[ot*4+r] = v; s += v; ss = fmaf(v, v, ss);
      }
    s  += __shfl_xor(s, 16, 64);  s  += __shfl_xor(s, 32, 64);
    ss += __shfl_xor(ss, 16, 64); ss += __shfl_xor(ss, 32, 64);
    const float mean = s * (1.f/64.f);
    const float rstd = rsqrtf(ss * (1.f/64.f) - mean*mean + 1e-5f);
    #pragma unroll
    for (int ot = 0; ot < 4; ot++)
      #pragma unroll
      for (int r = 0; r < 4; r++){
        const int row = ot*16 + qq*4 + r;
        y[ybase + (long)row*NCOL + colg] = (vals[ot*4+r]-mean)*rstd*sp[64+row] + sp[128+row];
      }
  }
}

extern "C" void kernel_launch(void* const* d_in, const int* in_sizes, int n_in,
                              void* d_out, int out_size, void* d_ws, size_t ws_size,
                              hipStream_t stream)
{
  const float* x    = (const float*)d_in[0];
  const float* g1   = (const float*)d_in[1];
  const float* b1   = (const float*)d_in[2];
  const float* wqkv = (const float*)d_in[3];
  const float* wout = (const float*)d_in[4];
  const float* bout = (const float*)d_in[5];
  const float* g2   = (const float*)d_in[6];
  const float* b2   = (const float*)d_in[7];
  float* y  = (float*)d_out;
  float* ws = (float*)d_ws;

  float* pctx = ws;                                        // [0, 4194304)
  float* O    = ws + 4194304;                              // 8192   (zeroed by kW)
  float* Zg   = ws + 4202496;                              // 256    (zeroed by kW)
  unsigned short* wbf  = (unsigned short*)(ws + 4202752);  // 24576 shorts -> 4215040 fl
  unsigned short* Mgbf = (unsigned short*)(ws + 4215040);  // 16384 shorts -> 4223232 fl
  unsigned short* qsg  = (unsigned short*)(ws + 4223232);  // 2*4*NCOL*32 shorts = 8388608 fl... ends 8417536 fl (33.7MB)

  hipLaunchKernelGGL(kW,  dim3(96),   dim3(256), 0, stream, wqkv, wbf, O);
  hipLaunchKernelGGL(kA,  dim3(1024), dim3(256), 0, stream, x, g1, b1, wbf, pctx, Zg, qsg);
  hipLaunchKernelGGL(kR1, dim3(256),  dim3(256), 0, stream, pctx, O);
  hipLaunchKernelGGL(kM,  dim3(64),   dim3(256), 0, stream, O, Zg, wout, Mgbf);
  hipLaunchKernelGGL(kC,  dim3(1024), dim3(256), 0, stream, qsg, Mgbf, bout, g2, b2, y);
}

// Round 12
// 203.005 us; speedup vs baseline: 2.7416x; 1.0649x over previous
//
#include <hip/hip_runtime.h>

// LinearAttention fused, MFMA (bf16 in / fp32 acc). 5-kernel pipeline.
//   kW : zero O/Zg + pre-convert w_qkv (384x64) -> bf16
//   kA : r10-exact (r4 body + xng bf16 mirror store). NO q-phase: r11 showed that
//        co-locating q-phase with cc[4][2][2] makes the compiler pick VGPR=88 and
//        spill half of cc (~33MB scratch WRITE). Split phases -> clean codegen.
//   kR1: pctx -> O (r4 exact).
//   kM : Mg = wout @ ctx / Z -> bf16 Mgbf, computed ONCE (r4 exact).
//        Mgbf ALIASES pctx[0..4096) — pctx is dead after kR1, so footprint stays
//        at r10's harness-verified 12,603,648 floats.
//   kC : slim front (bx from cached xng, r10-verified) -> stage Mgbf -> q GEMM ->
//        softmax (shfl) -> y = Mg @ qs -> +b_out -> LN2. One LN pass total.
#define NCOL 131072
#define CH 64

typedef float floatx4 __attribute__((ext_vector_type(4)));
typedef __bf16 bf16x8 __attribute__((ext_vector_type(8)));
typedef unsigned int u32x4 __attribute__((ext_vector_type(4)));
typedef unsigned int u32x2 __attribute__((ext_vector_type(2)));

union FragU { u32x4 q; bf16x8 v; unsigned short us[8]; };

__device__ __forceinline__ unsigned short bfb(float f){
  union { __bf16 h; unsigned short s; } u; u.h = (__bf16)f; return u.s;
}
__device__ __forceinline__ float bf2f(unsigned short h){
  union { unsigned u; float f; } x{(unsigned)h << 16};
  return x.f;
}

// LN over 64 channels for column (thread t) -> bf16 column at xn_s[t][0..63] (stride 72).
// If xg != null, also mirror the column to global (contiguous 128B per thread).
__device__ __forceinline__ void ln_stage(const float* __restrict__ xp,
    const float* __restrict__ g, const float* __restrict__ bb,
    unsigned short* __restrict__ xn_s, int t, unsigned short* __restrict__ xg)
{
  float xv[64]; float s = 0.f, ss = 0.f;
  #pragma unroll
  for (int c = 0; c < 64; c++){ float u = xp[(long)c*NCOL]; xv[c] = u; s += u; ss = fmaf(u,u,ss); }
  const float mean = s * (1.f/64.f);
  const float rstd = rsqrtf(ss * (1.f/64.f) - mean*mean + 1e-5f);
  #pragma unroll
  for (int c = 0; c < 64; c++) xv[c] = (xv[c]-mean)*rstd*g[c] + bb[c];
  #pragma unroll
  for (int j = 0; j < 8; j++){
    FragU u;
    #pragma unroll
    for (int e = 0; e < 8; e++) u.v[e] = (__bf16)xv[j*8+e];
    *(u32x4*)(xn_s + t*72 + j*8) = u.q;
    if (xg) *(u32x4*)(xg + j*8) = u.q;
  }
}

// ---------------- kW: zero O+Zg, convert wqkv -> bf16 ----------------
__global__ __launch_bounds__(256) void kW(
    const float* __restrict__ wqkv, unsigned short* __restrict__ wbf, float* __restrict__ Oz)
{
  const int i = blockIdx.x*256 + threadIdx.x;   // grid 96 -> 24576 threads
  wbf[i] = bfb(wqkv[i]);                        // 384*64
  if (i < 8448) Oz[i] = 0.f;                    // O (8192) + Zg (256)
}

// ---------------- kA (r10 exact: r4 body + optional xn mirror) ----------------
__global__ __launch_bounds__(256) void kA(
    const float* __restrict__ x, const float* __restrict__ g1, const float* __restrict__ b1,
    const unsigned short* __restrict__ wbf, float* __restrict__ pctx, float* __restrict__ Zg,
    unsigned short* __restrict__ xng)
{
  __shared__ __align__(16) char smem[37888];
  unsigned short* xn_s = (unsigned short*)smem;             // [0,36864) staging (dead after bx)
  unsigned short* ek_s = (unsigned short*)smem;             // [0,16896)   alias
  unsigned short* v_s  = (unsigned short*)(smem + 16896);   // [16896,33792) alias
  float* Zp            = (float*)(smem + 33792);            // [33792,35840) : [w][128]

  const int t = threadIdx.x;
  const int bid = blockIdx.x;
  const int b = bid >> 9;
  const long col0 = (long)(bid & 511) * 256;
  const int w = t >> 6, lane = t & 63, qq = lane >> 4, l16 = lane & 15;

  ln_stage(x + (long)b*CH*NCOL + col0 + t, g1, b1, xn_s, t,
           xng ? xng + ((long)b*NCOL + col0 + t)*64 : (unsigned short*)nullptr);
  // in-wave read-back of own wave's columns (DS in-order per wave; no barrier)
  FragU bx[4][2];
  #pragma unroll
  for (int nt = 0; nt < 4; nt++)
    #pragma unroll
    for (int ks = 0; ks < 2; ks++)
      bx[nt][ks].q = *(const u32x4*)(xn_s + ((4*w+nt)*16 + l16)*72 + ks*32 + qq*8);
  __syncthreads();   // alias guard: all waves' bx loaded before ek/v overwrite xn

  floatx4 cc[4][2][2];
  #pragma unroll
  for (int h = 0; h < 4; h++)
    #pragma unroll
    for (int dt = 0; dt < 2; dt++)
      #pragma unroll
      for (int et = 0; et < 2; et++)
        cc[h][dt][et] = floatx4{0.f,0.f,0.f,0.f};

  #pragma unroll
  for (int h = 0; h < 4; h++){
    float zr[8];
    #pragma unroll
    for (int j = 0; j < 8; j++) zr[j] = 0.f;
    // k (rt 0,1) and v (rt 2,3) GEMM, 16 rows per rt; wave-private column slices
    #pragma unroll
    for (int rt = 0; rt < 4; rt++){
      const int row0 = ((rt < 2) ? 128 : 256) + h*32 + (rt & 1)*16;
      const unsigned short* wr = wbf + (row0 + l16)*64 + qq*8;
      FragU a0, a1;
      a0.q = *(const u32x4*)wr;
      a1.q = *(const u32x4*)(wr + 32);
      unsigned short* dst = ((rt < 2) ? ek_s : v_s) + ((rt & 1)*16 + qq*4)*264;
      #pragma unroll
      for (int nt = 0; nt < 4; nt++){
        floatx4 c = floatx4{0.f,0.f,0.f,0.f};
        c = __builtin_amdgcn_mfma_f32_16x16x32_bf16(a0.v, bx[nt][0].v, c, 0, 0, 0);
        c = __builtin_amdgcn_mfma_f32_16x16x32_bf16(a1.v, bx[nt][1].v, c, 0, 0, 0);
        const int colb = (4*w+nt)*16 + l16;
        if (rt < 2){
          #pragma unroll
          for (int r = 0; r < 4; r++){
            const float e = __expf(c[r]);
            dst[r*264 + colb] = bfb(e);
            zr[(rt & 1)*4 + r] += e;
          }
        } else {
          #pragma unroll
          for (int r = 0; r < 4; r++) dst[r*264 + colb] = bfb(c[r]);
        }
      }
    }
    // Z partial for this wave's 64 cols: butterfly over l16 lanes
    #pragma unroll
    for (int j = 0; j < 8; j++){
      float v = zr[j];
      v += __shfl_xor(v, 1, 64); v += __shfl_xor(v, 2, 64);
      v += __shfl_xor(v, 4, 64); v += __shfl_xor(v, 8, 64);
      if (l16 == 0) Zp[w*128 + h*32 + (j >> 2)*16 + qq*4 + (j & 3)] = v;
    }
    // ctx MFMAs: wave w covers its own cols [64w,64w+64); in-wave DS ordering
    #pragma unroll
    for (int kk = 0; kk < 2; kk++){
      const int ks2 = 2*w + kk;
      FragU ae[2], bv[2];
      #pragma unroll
      for (int dt = 0; dt < 2; dt++) ae[dt].q = *(const u32x4*)(ek_s + (dt*16 + l16)*264 + ks2*32 + qq*8);
      #pragma unroll
      for (int et = 0; et < 2; et++) bv[et].q = *(const u32x4*)(v_s + (et*16 + l16)*264 + ks2*32 + qq*8);
      #pragma unroll
      for (int dt = 0; dt < 2; dt++)
        #pragma unroll
        for (int et = 0; et < 2; et++)
          cc[h][dt][et] = __builtin_amdgcn_mfma_f32_16x16x32_bf16(ae[dt].v, bv[et].v, cc[h][dt][et], 0, 0, 0);
    }
  }
  __syncthreads();   // all waves done with ek/v and Zp writes

  if (t < 128){
    const float z = Zp[t] + Zp[128 + t] + Zp[256 + t] + Zp[384 + t];
    atomicAdd(&Zg[b*128 + t], z);   // t == h*32+d
  }

  // cross-wave ctx reduction, staged in 32 KiB (scr aliases ek_s/v_s; Zp untouched)
  float* scr = (float*)smem;
  if (w & 1){
    #pragma unroll
    for (int h = 0; h < 4; h++)
      #pragma unroll
      for (int dt = 0; dt < 2; dt++)
        #pragma unroll
        for (int et = 0; et < 2; et++)
          ((floatx4*)scr)[(w>>1)*1024 + (h*4 + dt*2 + et)*64 + lane] = cc[h][dt][et];
  }
  __syncthreads();
  if (!(w & 1)){
    #pragma unroll
    for (int h = 0; h < 4; h++)
      #pragma unroll
      for (int dt = 0; dt < 2; dt++)
        #pragma unroll
        for (int et = 0; et < 2; et++)
          cc[h][dt][et] += ((floatx4*)scr)[(w>>1)*1024 + (h*4 + dt*2 + et)*64 + lane];
  }
  __syncthreads();
  if (w == 2){
    #pragma unroll
    for (int h = 0; h < 4; h++)
      #pragma unroll
      for (int dt = 0; dt < 2; dt++)
        #pragma unroll
        for (int et = 0; et < 2; et++)
          ((floatx4*)scr)[(h*4 + dt*2 + et)*64 + lane] = cc[h][dt][et];
  }
  __syncthreads();
  if (w == 0){
    #pragma unroll
    for (int h = 0; h < 4; h++)
      #pragma unroll
      for (int dt = 0; dt < 2; dt++)
        #pragma unroll
        for (int et = 0; et < 2; et++){
          floatx4 r = cc[h][dt][et] + ((floatx4*)scr)[(h*4 + dt*2 + et)*64 + lane];
          *(floatx4*)(pctx + (long)bid*4096 + (h*4 + dt*2 + et)*256 + lane*4) = r;
        }
  }
}

// ---------------- kR1: coalesced partial reduction -> atomic accumulate (r4 exact) ----------------
__global__ __launch_bounds__(256) void kR1(
    const float* __restrict__ pctx, float* __restrict__ O)
{
  const int blk = blockIdx.x;          // 256 blocks
  const int b = blk >> 7;              // 0..1
  const int part = (blk >> 4) & 7;     // 0..7   (64 pctx rows each)
  const int chunk = blk & 15;          // 0..15  (256 r-columns each)
  const int t = threadIdx.x;
  const int r = chunk*256 + t;
  const float* p = pctx + ((long)(b*512 + part*64))*4096 + r;
  float s = 0.f;
  #pragma unroll 16
  for (int row = 0; row < 64; row++) s += p[(long)row*4096];
  atomicAdd(&O[b*4096 + r], s);        // 8-way contention per location
}

// ---------------- kM: fuse w_out and 1/Z into ctx, emit bf16 (r4 exact) ----------------
// NOTE: Mgbf aliases pctx[0..4096 floats) — pctx is dead once kR1 completed.
__global__ __launch_bounds__(256) void kM(
    const float* __restrict__ O, const float* __restrict__ Zg,
    const float* __restrict__ wout, unsigned short* __restrict__ Mgbf)
{
  const int idx = blockIdx.x*256 + threadIdx.x;  // 0..16383
  const int b = idx >> 13, rem = idx & 8191;
  const int h = rem >> 11, o = (rem >> 5) & 63, dd = rem & 31;
  const int dt = dd >> 4, qq = (dd >> 2) & 3, rg = dd & 3;
  float m = 0.f;
  #pragma unroll
  for (int ee = 0; ee < 32; ee++){
    const int et = ee >> 4, l16 = ee & 15;
    const int r = h*1024 + (dt*2 + et)*256 + (qq*16 + l16)*4 + rg;
    m = fmaf(wout[o*128 + h*32 + ee], O[b*4096 + r], m);
  }
  m /= Zg[b*128 + h*32 + dd];
  Mgbf[idx] = bfb(m);                  // idx == ((b*4+h)*64+o)*32+dd
}

// ---------------- shared kC body: Mg stage + q GEMM/softmax + PV + LN2 ----------------
__device__ __forceinline__ void kC_body(
    const unsigned short* __restrict__ wbf, const unsigned short* __restrict__ Mgbf,
    float* __restrict__ y, char* smem, const FragU bx[4][2],
    int t, int b, long col0, int w, int lane, int qq, int l16)
{
  unsigned short* qs_s = (unsigned short*)smem;             // [0,20480)
  unsigned short* Mg_s = (unsigned short*)(smem + 20480);   // [20480,36864)
  float* sp            = (float*)(smem + 36864);            // 192 floats

  // stage Mg[b]: 8192 shorts = 1024 x 16B, 256 threads x 4
  #pragma unroll
  for (int j = 0; j < 4; j++)
    ((u32x4*)Mg_s)[j*256 + t] = ((const u32x4*)(Mgbf + (long)b*8192))[j*256 + t];
  __syncthreads();   // Mg_s + sp visible

  floatx4 yacc[4][4];
  #pragma unroll
  for (int ot = 0; ot < 4; ot++)
    #pragma unroll
    for (int nt = 0; nt < 4; nt++)
      yacc[ot][nt] = floatx4{0.f,0.f,0.f,0.f};

  #pragma unroll
  for (int h = 0; h < 4; h++){
    // q GEMM -> exp -> in-register column softmax (shfl over qq lanes) -> qs_s
    FragU a00, a01, a10, a11;
    {
      const unsigned short* wr0 = wbf + (h*32 + l16)*64 + qq*8;
      const unsigned short* wr1 = wbf + (h*32 + 16 + l16)*64 + qq*8;
      a00.q = *(const u32x4*)wr0; a01.q = *(const u32x4*)(wr0 + 32);
      a10.q = *(const u32x4*)wr1; a11.q = *(const u32x4*)(wr1 + 32);
    }
    #pragma unroll
    for (int nt = 0; nt < 4; nt++){
      floatx4 c0 = floatx4{0.f,0.f,0.f,0.f};
      floatx4 c1 = floatx4{0.f,0.f,0.f,0.f};
      c0 = __builtin_amdgcn_mfma_f32_16x16x32_bf16(a00.v, bx[nt][0].v, c0, 0, 0, 0);
      c0 = __builtin_amdgcn_mfma_f32_16x16x32_bf16(a01.v, bx[nt][1].v, c0, 0, 0, 0);
      c1 = __builtin_amdgcn_mfma_f32_16x16x32_bf16(a10.v, bx[nt][0].v, c1, 0, 0, 0);
      c1 = __builtin_amdgcn_mfma_f32_16x16x32_bf16(a11.v, bx[nt][1].v, c1, 0, 0, 0);
      float e[8]; float s = 0.f;
      #pragma unroll
      for (int r = 0; r < 4; r++){ e[r] = __expf(c0[r]); s += e[r]; }
      #pragma unroll
      for (int r = 0; r < 4; r++){ e[4+r] = __expf(c1[r]); s += e[4+r]; }
      s += __shfl_xor(s, 16, 64); s += __shfl_xor(s, 32, 64);
      const float sc = 0.17677669529663687f / s;   // 32^-0.5 / sum
      const int colb = (4*w+nt)*16 + l16;
      u32x2 pk0, pk1;
      pk0[0] = (unsigned)bfb(e[0]*sc) | ((unsigned)bfb(e[1]*sc) << 16);
      pk0[1] = (unsigned)bfb(e[2]*sc) | ((unsigned)bfb(e[3]*sc) << 16);
      pk1[0] = (unsigned)bfb(e[4]*sc) | ((unsigned)bfb(e[5]*sc) << 16);
      pk1[1] = (unsigned)bfb(e[6]*sc) | ((unsigned)bfb(e[7]*sc) << 16);
      *(u32x2*)(qs_s + colb*40 + qq*4)      = pk0;
      *(u32x2*)(qs_s + colb*40 + 16 + qq*4) = pk1;
    }
    // y += M_h @ qs_h  (in-wave DS ordering: qs writes above precede these reads)
    #pragma unroll
    for (int ot = 0; ot < 4; ot++){
      FragU am;
      am.q = *(const u32x4*)(Mg_s + (h*64 + ot*16 + l16)*32 + qq*8);
      #pragma unroll
      for (int nt = 0; nt < 4; nt++){
        FragU bq; bq.q = *(const u32x4*)(qs_s + ((4*w+nt)*16 + l16)*40 + qq*8);
        yacc[ot][nt] = __builtin_amdgcn_mfma_f32_16x16x32_bf16(am.v, bq.v, yacc[ot][nt], 0, 0, 0);
      }
    }
  }

  // epilogue: +b_out, LN2 over 64 rows (rows live on lanes {l16, l16+16, l16+32, l16+48})
  const long ybase = (long)b*CH*NCOL;
  #pragma unroll
  for (int nt = 0; nt < 4; nt++){
    const long colg = col0 + (4*w+nt)*16 + l16;
    float vals[16]; float s = 0.f, ss = 0.f;
    #pragma unroll
    for (int ot = 0; ot < 4; ot++)
      #pragma unroll
      for (int r = 0; r < 4; r++){
        const float v = yacc[ot][nt][r] + sp[ot*16 + qq*4 + r];
        vals[ot*4+r] = v; s += v; ss = fmaf(v, v, ss);
      }
    s  += __shfl_xor(s, 16, 64);  s  += __shfl_xor(s, 32, 64);
    ss += __shfl_xor(ss, 16, 64); ss += __shfl_xor(ss, 32, 64);
    const float mean = s * (1.f/64.f);
    const float rstd = rsqrtf(ss * (1.f/64.f) - mean*mean + 1e-5f);
    #pragma unroll
    for (int ot = 0; ot < 4; ot++)
      #pragma unroll
      for (int r = 0; r < 4; r++){
        const int row = ot*16 + qq*4 + r;
        y[ybase + (long)row*NCOL + colg] = (vals[ot*4+r]-mean)*rstd*sp[64+row] + sp[128+row];
      }
  }
}

// ---------------- kCs: slim front (bx from cached xn; no LN) ----------------
__global__ __launch_bounds__(256) void kCs(
    const unsigned short* __restrict__ xng, const unsigned short* __restrict__ wbf,
    const unsigned short* __restrict__ Mgbf,
    const float* __restrict__ bout, const float* __restrict__ g2, const float* __restrict__ b2,
    float* __restrict__ y)
{
  __shared__ __align__(16) char smem[37632];
  float* sp = (float*)(smem + 36864);

  const int t = threadIdx.x;
  const int bid = blockIdx.x;
  const int b = bid >> 9;
  const long col0 = (long)(bid & 511) * 256;
  const int w = t >> 6, lane = t & 63, qq = lane >> 4, l16 = lane & 15;

  if (t < 64){ sp[t] = bout[t]; sp[64+t] = g2[t]; sp[128+t] = b2[t]; }
  FragU bx[4][2];
  #pragma unroll
  for (int nt = 0; nt < 4; nt++){
    const unsigned short* xr = xng + ((long)b*NCOL + col0 + (4*w+nt)*16 + l16)*64;
    #pragma unroll
    for (int ks = 0; ks < 2; ks++)
      bx[nt][ks].q = *(const u32x4*)(xr + ks*32 + qq*8);
  }
  kC_body(wbf, Mgbf, y, smem, bx, t, b, col0, w, lane, qq, l16);
}

// ---------------- kCf: fat front fallback (LN recompute) ----------------
__global__ __launch_bounds__(256) void kCf(
    const float* __restrict__ x, const float* __restrict__ g1, const float* __restrict__ b1,
    const unsigned short* __restrict__ wbf, const unsigned short* __restrict__ Mgbf,
    const float* __restrict__ bout, const float* __restrict__ g2, const float* __restrict__ b2,
    float* __restrict__ y)
{
  __shared__ __align__(16) char smem[37632];
  unsigned short* xn_s = (unsigned short*)smem;   // [0,36864) staging (dead after bx)
  float* sp            = (float*)(smem + 36864);

  const int t = threadIdx.x;
  const int bid = blockIdx.x;
  const int b = bid >> 9;
  const long col0 = (long)(bid & 511) * 256;
  const int w = t >> 6, lane = t & 63, qq = lane >> 4, l16 = lane & 15;

  if (t < 64){ sp[t] = bout[t]; sp[64+t] = g2[t]; sp[128+t] = b2[t]; }
  ln_stage(x + (long)b*CH*NCOL + col0 + t, g1, b1, xn_s, t, (unsigned short*)nullptr);
  FragU bx[4][2];
  #pragma unroll
  for (int nt = 0; nt < 4; nt++)
    #pragma unroll
    for (int ks = 0; ks < 2; ks++)
      bx[nt][ks].q = *(const u32x4*)(xn_s + ((4*w+nt)*16 + l16)*72 + ks*32 + qq*8);
  __syncthreads();   // xn dead before Mg_s/qs staging overwrites it
  kC_body(wbf, Mgbf, y, smem, bx, t, b, col0, w, lane, qq, l16);
}

extern "C" void kernel_launch(void* const* d_in, const int* in_sizes, int n_in,
                              void* d_out, int out_size, void* d_ws, size_t ws_size,
                              hipStream_t stream)
{
  const float* x    = (const float*)d_in[0];
  const float* g1   = (const float*)d_in[1];
  const float* b1   = (const float*)d_in[2];
  const float* wqkv = (const float*)d_in[3];
  const float* wout = (const float*)d_in[4];
  const float* bout = (const float*)d_in[5];
  const float* g2   = (const float*)d_in[6];
  const float* b2   = (const float*)d_in[7];
  float* y  = (float*)d_out;
  float* ws = (float*)d_ws;

  float* pctx = ws;                                        // [0, 4194304)
  unsigned short* Mgbf = (unsigned short*)ws;              // 16384 shorts, ALIASES pctx (dead after kR1)
  float* O    = ws + 4194304;                              // 8192   (zeroed by kW)
  float* Zg   = ws + 4202496;                              // 256    (zeroed by kW)
  unsigned short* wbf = (unsigned short*)(ws + 4202752);   // 24576 shorts -> 4215040 fl
  unsigned short* xng = (unsigned short*)(ws + 4215040);   // 16777216 shorts -> 12603648 fl
  const bool big = ws_size >= (size_t)12603648 * 4;        // r10-verified footprint

  hipLaunchKernelGGL(kW,  dim3(96),   dim3(256), 0, stream, wqkv, wbf, O);
  hipLaunchKernelGGL(kA,  dim3(1024), dim3(256), 0, stream, x, g1, b1, wbf, pctx, Zg,
                     big ? xng : (unsigned short*)nullptr);
  hipLaunchKernelGGL(kR1, dim3(256),  dim3(256), 0, stream, pctx, O);
  hipLaunchKernelGGL(kM,  dim3(64),   dim3(256), 0, stream, O, Zg, wout, Mgbf);
  if (big)
    hipLaunchKernelGGL(kCs, dim3(1024), dim3(256), 0, stream, xng, wbf, Mgbf, bout, g2, b2, y);
  else
    hipLaunchKernelGGL(kCf, dim3(1024), dim3(256), 0, stream, x, g1, b1, wbf, Mgbf, bout, g2, b2, y);
}